// Round 8
// baseline (1304.253 us; speedup 1.0000x reference)
//
#include <hip/hip_runtime.h>

// WeightedGCN: 2-layer GCNConv (PyG), N=100K, E=1.25M, D=64, fp32 in/out.
// R8: kill csr + k_bucket_fill. Aggregate per BUCKET (block = 128 nodes) with a
//     128x68-padded fp32 LDS accumulator: stream bucketed edges coalesced (256/batch,
//     dis[src] pre-gathered at stage time), unroll-4 clamped H-row gathers (16 rows
//     in flight/wave), ds_add_f32 scatter into LDS, coalesced epilogue.
//     k_bucket_stats -> dis only. Scatter/bin edge loads vectorized x2.
// Build: two-level counting sort, zero per-edge global atomics (R5).

typedef unsigned int u32;
typedef unsigned short u16;

#define NBKT 1024        // coarse buckets
#define LSH 7            // 128 nodes per bucket
#define SRCBITS 17       // N=100K < 2^17
#define SRCMASK ((1u << SRCBITS) - 1u)

__device__ inline u16 f2bf(float f) {            // RNE fp32->bf16
  u32 u = __float_as_uint(f);
  u32 r = u + 0x7FFFu + ((u >> 16) & 1u);
  return (u16)(r >> 16);
}
__device__ inline float bf_lo(u32 p) { return __uint_as_float(p << 16); }
__device__ inline float bf_hi(u32 p) { return __uint_as_float(p & 0xFFFF0000u); }

// ---- build pass 1: per-block bucket histogram (LDS atomics only) ----
__global__ void k_bin(const int* __restrict__ ei, u32* __restrict__ blockcnt,
                      int E, int chunk) {
  __shared__ u32 hist[NBKT];
  for (int i = threadIdx.x; i < NBKT; i += 256) hist[i] = 0u;
  __syncthreads();
  int e0 = blockIdx.x * chunk;
  int e1 = min(E, e0 + chunk);
  for (int e = e0 + (threadIdx.x << 1); e < e1; e += 512) {
    if (e + 1 < e1) {
      int2 dd = *(const int2*)(ei + E + e);
      atomicAdd(&hist[dd.x >> LSH], 1u);
      atomicAdd(&hist[dd.y >> LSH], 1u);
    } else {
      atomicAdd(&hist[ei[E + e] >> LSH], 1u);
    }
  }
  __syncthreads();
  for (int i = threadIdx.x; i < NBKT; i += 256)
    blockcnt[i * 256 + blockIdx.x] = hist[i];
}

// ---- build pass 2a: exclusive scan of each bucket row (one wave/row) ----
__global__ void k_scan_rows(u32* __restrict__ blockcnt, u32* __restrict__ bucket_total) {
  int wid = blockIdx.x * 4 + (threadIdx.x >> 6);
  int lane = threadIdx.x & 63;
  u32* row = blockcnt + (size_t)wid * 256;
  uint4 v = ((uint4*)row)[lane];
  u32 s = v.x + v.y + v.z + v.w;
  u32 inc = s;
  #pragma unroll
  for (int d = 1; d < 64; d <<= 1) {
    u32 t = __shfl_up(inc, d);
    if (lane >= d) inc += t;
  }
  u32 excl = inc - s;
  uint4 o;
  o.x = excl; o.y = excl + v.x; o.z = o.y + v.y; o.w = o.z + v.z;
  ((uint4*)row)[lane] = o;
  if (lane == 63) bucket_total[wid] = inc;
}

// ---- build pass 2b: exclusive scan over 1024 bucket totals ----
__global__ void k_scan_buckets(const u32* __restrict__ bucket_total,
                               u32* __restrict__ bucket_start) {
  __shared__ u32 a[NBKT], b[NBKT];
  int t = threadIdx.x;                              // 1024 threads
  a[t] = bucket_total[t];
  __syncthreads();
  u32* s = a; u32* d = b;
  for (int st = 1; st < NBKT; st <<= 1) {
    d[t] = s[t] + (t >= st ? s[t - st] : 0u);
    __syncthreads();
    u32* tmp = s; s = d; d = tmp;
  }
  bucket_start[t + 1] = s[t];
  if (t == 0) bucket_start[0] = 0u;
}

// ---- build pass 3 (+ fused GEMM-1): scatter edges into bucket regions ----
__global__ void k_scatter_gemm(const int* __restrict__ ei, const float* __restrict__ w,
                               const u32* __restrict__ blockcnt, const u32* __restrict__ bucket_start,
                               uint2* __restrict__ bucketed,
                               const float* __restrict__ X, const float* __restrict__ W,
                               u16* __restrict__ H, int N, int E, int chunk) {
  __shared__ float Wt[64 * 65];                     // aliased by scatter cursors
  int tid = threadIdx.x;
  if ((int)blockIdx.x < 256) {
    u32* base = (u32*)Wt;
    for (int i = tid; i < NBKT; i += 256)
      base[i] = blockcnt[(size_t)i * 256 + blockIdx.x] + bucket_start[i];
    __syncthreads();
    int e0 = blockIdx.x * chunk, e1 = min(E, e0 + chunk);
    for (int e = e0 + (tid << 1); e < e1; e += 512) {
      if (e + 1 < e1) {                            // 2 edges: vector loads, 2x MLP
        int2 ss = *(const int2*)(ei + e);
        int2 dd = *(const int2*)(ei + E + e);
        float2 wv = *(const float2*)(w + e);
        u32 p0 = atomicAdd(&base[dd.x >> LSH], 1u);
        u32 p1 = atomicAdd(&base[dd.y >> LSH], 1u);
        bucketed[p0] = make_uint2((u32)ss.x | ((u32)(dd.x & 127) << SRCBITS), __float_as_uint(wv.x));
        bucketed[p1] = make_uint2((u32)ss.y | ((u32)(dd.y & 127) << SRCBITS), __float_as_uint(wv.y));
      } else {
        int s = ei[e], d = ei[E + e];
        u32 pos = atomicAdd(&base[d >> LSH], 1u);
        bucketed[pos] = make_uint2((u32)s | ((u32)(d & 127) << SRCBITS), __float_as_uint(w[e]));
      }
    }
    return;
  }
  // GEMM branch: H1 = X @ W1^T -> bf16
  for (int i = tid; i < 4096; i += 256) Wt[(i & 63) * 65 + (i >> 6)] = W[i];
  __syncthreads();
  int lane = tid & 63, wv4 = tid >> 6;
  int row0 = ((int)blockIdx.x - 256) * 16 + wv4 * 4;
  if (row0 >= N) return;
  if (row0 + 3 < N) {
    const float4* x0 = (const float4*)(X + (size_t)row0 * 64);
    float a0 = 0.f, a1 = 0.f, a2 = 0.f, a3 = 0.f;
    #pragma unroll
    for (int k4 = 0; k4 < 16; ++k4) {
      float4 xa = x0[k4];
      float4 xb = x0[16 + k4];
      float4 xc = x0[32 + k4];
      float4 xd = x0[48 + k4];
      int k = k4 << 2;
      float w0 = Wt[k * 65 + lane], w1 = Wt[(k + 1) * 65 + lane];
      float w2 = Wt[(k + 2) * 65 + lane], w3 = Wt[(k + 3) * 65 + lane];
      a0 = fmaf(xa.x, w0, fmaf(xa.y, w1, fmaf(xa.z, w2, fmaf(xa.w, w3, a0))));
      a1 = fmaf(xb.x, w0, fmaf(xb.y, w1, fmaf(xb.z, w2, fmaf(xb.w, w3, a1))));
      a2 = fmaf(xc.x, w0, fmaf(xc.y, w1, fmaf(xc.z, w2, fmaf(xc.w, w3, a2))));
      a3 = fmaf(xd.x, w0, fmaf(xd.y, w1, fmaf(xd.z, w2, fmaf(xd.w, w3, a3))));
    }
    H[(size_t)row0 * 64 + lane]       = f2bf(a0);
    H[(size_t)(row0 + 1) * 64 + lane] = f2bf(a1);
    H[(size_t)(row0 + 2) * 64 + lane] = f2bf(a2);
    H[(size_t)(row0 + 3) * 64 + lane] = f2bf(a3);
  } else {
    const float* x0 = X + (size_t)row0 * 64;
    for (int r = 0; r < 4 && row0 + r < N; ++r) {
      float a = 0.f;
      for (int k = 0; k < 64; ++k) a = fmaf(x0[r * 64 + k], Wt[k * 65 + lane], a);
      H[(size_t)(row0 + r) * 64 + lane] = f2bf(a);
    }
  }
}

// ---- build pass 4: per-bucket weighted-degree -> dis (packed LDS histogram) ----
__global__ void k_bucket_stats(const uint2* __restrict__ bucketed,
                               const u32* __restrict__ bucket_start,
                               float* __restrict__ dis, int N) {
  __shared__ u32 hist[128];
  int b = blockIdx.x, tid = threadIdx.x;
  if (tid < 128) hist[tid] = 0u;
  __syncthreads();
  u32 s0 = bucket_start[b], s1 = bucket_start[b + 1];
  for (u32 p = s0 + tid; p < s1; p += 256) {
    uint2 ed = bucketed[p];
    u32 local = ed.x >> SRCBITS;
    u32 wfix = (u32)(__uint_as_float(ed.y) * 262144.0f);   // 18 frac bits, sum < 2^24
    atomicAdd(&hist[local], wfix);
  }
  __syncthreads();
  int node = b * 128 + tid;
  if (tid < 128 && node < N) {
    float wsum = (float)hist[tid] * (1.0f / 262144.0f);
    dis[node] = rsqrtf(1.0f + wsum);             // deg >= 1 (self-loop)
  }
}

// ---- GEMM (layer 2): fp32 in, bf16 out ----
__global__ void k_gemm(const float* __restrict__ X, const float* __restrict__ W,
                       u16* __restrict__ H, int N) {
  __shared__ float Wt[64][65];
  int tid = threadIdx.x;
  #pragma unroll
  for (int i = tid; i < 4096; i += 256) Wt[i & 63][i >> 6] = W[i];
  __syncthreads();
  int lane = tid & 63, wv = tid >> 6;
  int row0 = blockIdx.x * 16 + wv * 4;
  if (row0 >= N) return;
  if (row0 + 3 < N) {
    const float4* x0 = (const float4*)(X + (size_t)row0 * 64);
    float a0 = 0.f, a1 = 0.f, a2 = 0.f, a3 = 0.f;
    #pragma unroll
    for (int k4 = 0; k4 < 16; ++k4) {
      float4 xa = x0[k4];
      float4 xb = x0[16 + k4];
      float4 xc = x0[32 + k4];
      float4 xd = x0[48 + k4];
      int k = k4 << 2;
      float w0 = Wt[k][lane], w1 = Wt[k + 1][lane], w2 = Wt[k + 2][lane], w3 = Wt[k + 3][lane];
      a0 = fmaf(xa.x, w0, fmaf(xa.y, w1, fmaf(xa.z, w2, fmaf(xa.w, w3, a0))));
      a1 = fmaf(xb.x, w0, fmaf(xb.y, w1, fmaf(xb.z, w2, fmaf(xb.w, w3, a1))));
      a2 = fmaf(xc.x, w0, fmaf(xc.y, w1, fmaf(xc.z, w2, fmaf(xc.w, w3, a2))));
      a3 = fmaf(xd.x, w0, fmaf(xd.y, w1, fmaf(xd.z, w2, fmaf(xd.w, w3, a3))));
    }
    H[(size_t)row0 * 64 + lane]       = f2bf(a0);
    H[(size_t)(row0 + 1) * 64 + lane] = f2bf(a1);
    H[(size_t)(row0 + 2) * 64 + lane] = f2bf(a2);
    H[(size_t)(row0 + 3) * 64 + lane] = f2bf(a3);
  } else {
    const float* x0 = X + (size_t)row0 * 64;
    for (int r = 0; r < 4 && row0 + r < N; ++r) {
      float a = 0.f;
      for (int k = 0; k < 64; ++k) a = fmaf(x0[r * 64 + k], Wt[k][lane], a);
      H[(size_t)(row0 + r) * 64 + lane] = f2bf(a);
    }
  }
}

// ---- aggregation: one block per bucket (128 nodes), LDS fp32 accumulator.
// Streams bucketed edges coalesced (256/batch, dis[src] pre-gathered), 16-lane
// groups do unroll-4 clamped H-row gathers, ds_add_f32 into acc[128][68].
template <int RELU>
__global__ __launch_bounds__(256) void k_agg_bucket(
    const uint2* __restrict__ bucketed, const u32* __restrict__ bucket_start,
    const float* __restrict__ dis, const u16* __restrict__ H,
    const float* __restrict__ bias, float* __restrict__ Y, int N) {
  __shared__ float acc[128 * 68];                  // pad 68: spreads node rows over banks
  __shared__ float dloc[128];
  __shared__ uint2 ebuf[256];
  __shared__ float edis[256];
  int tid = threadIdx.x;
  int b = blockIdx.x;
  u32 s0 = bucket_start[b], s1 = bucket_start[b + 1];
  for (int i = tid; i < 128 * 68; i += 256) acc[i] = 0.f;
  if (tid < 128) {
    int node = b * 128 + tid;
    dloc[tid] = (node < N) ? dis[node] : 0.f;
  }
  __syncthreads();
  int g = tid >> 4, gl = tid & 15, fid = gl << 2;
  for (u32 base = s0; base < s1; base += 256) {
    int m = (int)min(256u, s1 - base);
    if (tid < m) {
      uint2 e = bucketed[base + tid];              // coalesced edge stage
      ebuf[tid] = e;
      edis[tid] = dis[e.x & SRCMASK];              // src-side norm, pre-gathered
    }
    __syncthreads();
    int mm1 = m - 1;
    for (int jb = 0; jb < m; jb += 64) {
      int p0 = jb + g;
      int q0 = min(p0, mm1), q1 = min(p0 + 16, mm1);
      int q2 = min(p0 + 32, mm1), q3 = min(p0 + 48, mm1);
      uint2 e0 = ebuf[q0], e1 = ebuf[q1], e2 = ebuf[q2], e3 = ebuf[q3];
      uint2 h0 = *(const uint2*)(H + (size_t)(e0.x & SRCMASK) * 64 + fid);  // 4 rows
      uint2 h1 = *(const uint2*)(H + (size_t)(e1.x & SRCMASK) * 64 + fid);  // in
      uint2 h2 = *(const uint2*)(H + (size_t)(e2.x & SRCMASK) * 64 + fid);  // flight
      uint2 h3 = *(const uint2*)(H + (size_t)(e3.x & SRCMASK) * 64 + fid);
      if (p0 < m) {
        float c = edis[q0] * __uint_as_float(e0.y) * dloc[e0.x >> SRCBITS];
        float* a = &acc[(e0.x >> SRCBITS) * 68 + fid];
        atomicAdd(a + 0, bf_lo(h0.x) * c); atomicAdd(a + 1, bf_hi(h0.x) * c);
        atomicAdd(a + 2, bf_lo(h0.y) * c); atomicAdd(a + 3, bf_hi(h0.y) * c);
      }
      if (p0 + 16 < m) {
        float c = edis[q1] * __uint_as_float(e1.y) * dloc[e1.x >> SRCBITS];
        float* a = &acc[(e1.x >> SRCBITS) * 68 + fid];
        atomicAdd(a + 0, bf_lo(h1.x) * c); atomicAdd(a + 1, bf_hi(h1.x) * c);
        atomicAdd(a + 2, bf_lo(h1.y) * c); atomicAdd(a + 3, bf_hi(h1.y) * c);
      }
      if (p0 + 32 < m) {
        float c = edis[q2] * __uint_as_float(e2.y) * dloc[e2.x >> SRCBITS];
        float* a = &acc[(e2.x >> SRCBITS) * 68 + fid];
        atomicAdd(a + 0, bf_lo(h2.x) * c); atomicAdd(a + 1, bf_hi(h2.x) * c);
        atomicAdd(a + 2, bf_lo(h2.y) * c); atomicAdd(a + 3, bf_hi(h2.y) * c);
      }
      if (p0 + 48 < m) {
        float c = edis[q3] * __uint_as_float(e3.y) * dloc[e3.x >> SRCBITS];
        float* a = &acc[(e3.x >> SRCBITS) * 68 + fid];
        atomicAdd(a + 0, bf_lo(h3.x) * c); atomicAdd(a + 1, bf_hi(h3.x) * c);
        atomicAdd(a + 2, bf_lo(h3.y) * c); atomicAdd(a + 3, bf_hi(h3.y) * c);
      }
    }
    __syncthreads();                               // before ebuf reuse
  }
  // epilogue: self-loop + bias (+ReLU), coalesced fp32 store
  for (int i = tid; i < 2048; i += 256) {          // 128 nodes x 16 float4 slots
    int nl = i >> 4;
    int f = (i & 15) << 2;
    int node = b * 128 + nl;
    if (node >= N) continue;
    float dd = dloc[nl] * dloc[nl];
    uint2 hs = *(const uint2*)(H + (size_t)node * 64 + f);
    float4 b4 = *(const float4*)(bias + f);
    const float* a = &acc[nl * 68 + f];
    float4 v;
    v.x = fmaf(bf_lo(hs.x), dd, a[0]) + b4.x;
    v.y = fmaf(bf_hi(hs.x), dd, a[1]) + b4.y;
    v.z = fmaf(bf_lo(hs.y), dd, a[2]) + b4.z;
    v.w = fmaf(bf_hi(hs.y), dd, a[3]) + b4.w;
    if (RELU) {
      v.x = fmaxf(v.x, 0.f); v.y = fmaxf(v.y, 0.f);
      v.z = fmaxf(v.z, 0.f); v.w = fmaxf(v.w, 0.f);
    }
    *(float4*)(Y + (size_t)node * 64 + f) = v;
  }
}

extern "C" void kernel_launch(void* const* d_in, const int* in_sizes, int n_in,
                              void* d_out, int out_size, void* d_ws, size_t ws_size,
                              hipStream_t stream) {
  const float* x  = (const float*)d_in[0];
  const int*   ei = (const int*)d_in[1];
  const float* w  = (const float*)d_in[2];
  const float* W1 = (const float*)d_in[3];
  const float* b1 = (const float*)d_in[4];
  const float* W2 = (const float*)d_in[5];
  const float* b2 = (const float*)d_in[6];
  const int N = in_sizes[0] / 64;
  const int E = in_sizes[2];

  char* ws = (char*)d_ws;
  size_t off = 0;
  auto alloc = [&](size_t bytes) -> char* {
    char* p = ws + off;
    off = (off + bytes + 255) & ~(size_t)255;
    return p;
  };
  u32*   blockcnt     = (u32*)  alloc((size_t)NBKT * 256 * 4);
  u32*   bucket_total = (u32*)  alloc((size_t)NBKT * 4);
  u32*   bucket_start = (u32*)  alloc((size_t)(NBKT + 1) * 4);
  uint2* bucketed     = (uint2*)alloc((size_t)E * 8);
  float* dis          = (float*)alloc((size_t)N * 4);
  u16*   h1           = (u16*)  alloc((size_t)N * 64 * 2);
  u16*   h2           = (u16*)  alloc((size_t)N * 64 * 2);
  float* ybuf         = (float*)d_out;             // layer-1 activations (fp32)

  const int chunk = ((E + 511) / 512) * 2;         // even, 256 blocks cover E
  const int nbG = (N + 15) / 16;
  const int nbB = (N + 127) >> LSH;

  k_bin<<<256, 256, 0, stream>>>(ei, blockcnt, E, chunk);
  k_scan_rows<<<256, 256, 0, stream>>>(blockcnt, bucket_total);
  k_scan_buckets<<<1, 1024, 0, stream>>>(bucket_total, bucket_start);
  k_scatter_gemm<<<256 + nbG, 256, 0, stream>>>(ei, w, blockcnt, bucket_start,
                                                bucketed, x, W1, h1, N, E, chunk);
  k_bucket_stats<<<nbB, 256, 0, stream>>>(bucketed, bucket_start, dis, N);

  k_agg_bucket<1><<<nbB, 256, 0, stream>>>(bucketed, bucket_start, dis, h1, b1, ybuf, N);
  k_gemm<<<nbG, 256, 0, stream>>>(ybuf, W2, h2, N);
  k_agg_bucket<0><<<nbB, 256, 0, stream>>>(bucketed, bucket_start, dis, h2, b2,
                                           (float*)d_out, N);
}

// Round 9
// 308.673 us; speedup vs baseline: 4.2254x; 4.2254x over previous
//
#include <hip/hip_runtime.h>

// WeightedGCN: 2-layer GCNConv (PyG), N=100K, E=1.25M, D=64, fp32 in/out.
// R9 (base = R7's 316us; R8's LDS-atomic bucket-agg was 4x worse - reverted):
//  (a) Norm folded into tables: H' = dis*H (pre-scaled rows), csr = {src, RAW w},
//      agg: out = dis_d*(sum w*H'[s] + H'[d]) + b.  Fill no longer needs dis ->
//      stats+fill+H-scale fused into ONE kernel (pass2 re-read is L2-hot).
//  (b) NBKT 1024->256 (512 nodes/bucket): scatter appends ~19 contiguous edges
//      per block-bucket sub-range (was ~4.8) -> scattered-write sectors ~3x fewer.
//  (c) 8 dispatches (was 9).
// Aggregate keeps R7 shape: wave/node, 4 edge-groups x 16 lanes, unroll-4 clamped.

typedef unsigned int u32;
typedef unsigned short u16;

#define NBKT 256         // coarse buckets
#define LSH 9            // 512 nodes per bucket
#define BNODES 512
#define SRCBITS 17       // N=100K < 2^17
#define SRCMASK ((1u << SRCBITS) - 1u)

__device__ inline u16 f2bf(float f) {            // RNE fp32->bf16
  u32 u = __float_as_uint(f);
  u32 r = u + 0x7FFFu + ((u >> 16) & 1u);
  return (u16)(r >> 16);
}
__device__ inline float bf_lo(u32 p) { return __uint_as_float(p << 16); }
__device__ inline float bf_hi(u32 p) { return __uint_as_float(p & 0xFFFF0000u); }

// block-wide (256 thr) exclusive scan of one u32/thread; wsum = LDS[4] scratch.
__device__ inline u32 blockscan256_excl(u32 val, u32* wsum) {
  int lane = threadIdx.x & 63, wv = threadIdx.x >> 6;
  u32 inc = val;
  #pragma unroll
  for (int d = 1; d < 64; d <<= 1) {
    u32 t = __shfl_up(inc, d);
    if (lane >= d) inc += t;
  }
  if (lane == 63) wsum[wv] = inc;
  __syncthreads();
  u32 off = 0;
  #pragma unroll
  for (int i = 0; i < 4; ++i) if (i < wv) off += wsum[i];
  return off + inc - val;
}

// ---- build pass 1: per-block bucket histogram (LDS atomics only) ----
__global__ void k_bin(const int* __restrict__ ei, u32* __restrict__ blockcnt,
                      int E, int chunk) {
  __shared__ u32 hist[NBKT];
  if (threadIdx.x < NBKT) hist[threadIdx.x] = 0u;
  __syncthreads();
  int e0 = blockIdx.x * chunk;
  int e1 = min(E, e0 + chunk);
  for (int e = e0 + (threadIdx.x << 1); e < e1; e += 512) {
    if (e + 1 < e1) {
      int2 dd = *(const int2*)(ei + E + e);
      atomicAdd(&hist[dd.x >> LSH], 1u);
      atomicAdd(&hist[dd.y >> LSH], 1u);
    } else {
      atomicAdd(&hist[ei[E + e] >> LSH], 1u);
    }
  }
  __syncthreads();
  if (threadIdx.x < NBKT)
    blockcnt[threadIdx.x * 256 + blockIdx.x] = hist[threadIdx.x];
}

// ---- build pass 2a: exclusive scan of each bucket row (one wave/row) ----
__global__ void k_scan_rows(u32* __restrict__ blockcnt, u32* __restrict__ bucket_total) {
  int wid = blockIdx.x * 4 + (threadIdx.x >> 6);   // 0..NBKT-1
  int lane = threadIdx.x & 63;
  u32* row = blockcnt + (size_t)wid * 256;
  uint4 v = ((uint4*)row)[lane];
  u32 s = v.x + v.y + v.z + v.w;
  u32 inc = s;
  #pragma unroll
  for (int d = 1; d < 64; d <<= 1) {
    u32 t = __shfl_up(inc, d);
    if (lane >= d) inc += t;
  }
  u32 excl = inc - s;
  uint4 o;
  o.x = excl; o.y = excl + v.x; o.z = o.y + v.y; o.w = o.z + v.z;
  ((uint4*)row)[lane] = o;
  if (lane == 63) bucket_total[wid] = inc;
}

// ---- build pass 2b: exclusive scan over NBKT bucket totals ----
__global__ void k_scan_buckets(const u32* __restrict__ bucket_total,
                               u32* __restrict__ bucket_start) {
  __shared__ u32 wsum[4];
  int t = threadIdx.x;                              // 256 threads
  u32 v = bucket_total[t];
  u32 excl = blockscan256_excl(v, wsum);
  bucket_start[t] = excl;
  if (t == 255) bucket_start[256] = excl + v;
}

// ---- build pass 3 (+ fused GEMM-1): scatter edges into bucket regions ----
__global__ void k_scatter_gemm(const int* __restrict__ ei, const float* __restrict__ w,
                               const u32* __restrict__ blockcnt, const u32* __restrict__ bucket_start,
                               uint2* __restrict__ bucketed,
                               const float* __restrict__ X, const float* __restrict__ W,
                               u16* __restrict__ H, int N, int E, int chunk) {
  __shared__ float Wt[64 * 65];
  __shared__ u32 base[NBKT];
  int tid = threadIdx.x;
  if ((int)blockIdx.x < 256) {
    if (tid < NBKT)
      base[tid] = blockcnt[(size_t)tid * 256 + blockIdx.x] + bucket_start[tid];
    __syncthreads();
    int e0 = blockIdx.x * chunk, e1 = min(E, e0 + chunk);
    for (int e = e0 + (tid << 1); e < e1; e += 512) {
      if (e + 1 < e1) {
        int2 ss = *(const int2*)(ei + e);
        int2 dd = *(const int2*)(ei + E + e);
        float2 wv = *(const float2*)(w + e);
        u32 p0 = atomicAdd(&base[dd.x >> LSH], 1u);
        u32 p1 = atomicAdd(&base[dd.y >> LSH], 1u);
        bucketed[p0] = make_uint2((u32)ss.x | ((u32)(dd.x & (BNODES - 1)) << SRCBITS),
                                  __float_as_uint(wv.x));
        bucketed[p1] = make_uint2((u32)ss.y | ((u32)(dd.y & (BNODES - 1)) << SRCBITS),
                                  __float_as_uint(wv.y));
      } else {
        int s = ei[e], d = ei[E + e];
        u32 pos = atomicAdd(&base[d >> LSH], 1u);
        bucketed[pos] = make_uint2((u32)s | ((u32)(d & (BNODES - 1)) << SRCBITS),
                                   __float_as_uint(w[e]));
      }
    }
    return;
  }
  // GEMM branch: H1 = X @ W1^T -> bf16 (UNscaled; statsfill scales by dis later)
  for (int i = tid; i < 4096; i += 256) Wt[(i & 63) * 65 + (i >> 6)] = W[i];
  __syncthreads();
  int lane = tid & 63, wv4 = tid >> 6;
  int row0 = ((int)blockIdx.x - 256) * 16 + wv4 * 4;
  if (row0 >= N) return;
  if (row0 + 3 < N) {
    const float4* x0 = (const float4*)(X + (size_t)row0 * 64);
    float a0 = 0.f, a1 = 0.f, a2 = 0.f, a3 = 0.f;
    #pragma unroll
    for (int k4 = 0; k4 < 16; ++k4) {
      float4 xa = x0[k4];
      float4 xb = x0[16 + k4];
      float4 xc = x0[32 + k4];
      float4 xd = x0[48 + k4];
      int k = k4 << 2;
      float w0 = Wt[k * 65 + lane], w1 = Wt[(k + 1) * 65 + lane];
      float w2 = Wt[(k + 2) * 65 + lane], w3 = Wt[(k + 3) * 65 + lane];
      a0 = fmaf(xa.x, w0, fmaf(xa.y, w1, fmaf(xa.z, w2, fmaf(xa.w, w3, a0))));
      a1 = fmaf(xb.x, w0, fmaf(xb.y, w1, fmaf(xb.z, w2, fmaf(xb.w, w3, a1))));
      a2 = fmaf(xc.x, w0, fmaf(xc.y, w1, fmaf(xc.z, w2, fmaf(xc.w, w3, a2))));
      a3 = fmaf(xd.x, w0, fmaf(xd.y, w1, fmaf(xd.z, w2, fmaf(xd.w, w3, a3))));
    }
    H[(size_t)row0 * 64 + lane]       = f2bf(a0);
    H[(size_t)(row0 + 1) * 64 + lane] = f2bf(a1);
    H[(size_t)(row0 + 2) * 64 + lane] = f2bf(a2);
    H[(size_t)(row0 + 3) * 64 + lane] = f2bf(a3);
  } else {
    const float* x0 = X + (size_t)row0 * 64;
    for (int r = 0; r < 4 && row0 + r < N; ++r) {
      float a = 0.f;
      for (int k = 0; k < 64; ++k) a = fmaf(x0[r * 64 + k], Wt[k * 65 + lane], a);
      H[(size_t)(row0 + r) * 64 + lane] = f2bf(a);
    }
  }
}

// ---- build pass 4 (fused): hist -> dis + info; reorder csr {src, raw w}
//      (pass2 over L2-hot bucket slice); scale own H rows: H' = dis*H. ----
__global__ void k_statsfill(const uint2* __restrict__ bucketed,
                            const u32* __restrict__ bucket_start,
                            float* __restrict__ dis, int4* __restrict__ info,
                            int2* __restrict__ csr, u16* __restrict__ H, int N) {
  __shared__ u32 hist[BNODES];
  __shared__ u32 cur[BNODES];
  __shared__ float disl[BNODES];
  __shared__ u32 wsum[4];
  int b = blockIdx.x, tid = threadIdx.x;
  for (int i = tid; i < BNODES; i += 256) hist[i] = 0u;
  __syncthreads();
  u32 s0 = bucket_start[b], s1 = bucket_start[b + 1];
  for (u32 p = s0 + tid; p < s1; p += 256) {
    uint2 ed = bucketed[p];
    u32 local = ed.x >> SRCBITS;
    u32 wfix = (u32)(__uint_as_float(ed.y) * 262144.0f);   // 18 frac bits
    atomicAdd(&hist[local], (1u << 24) | wfix);            // cnt<<24 | wsum
  }
  __syncthreads();
  u32 h0 = hist[2 * tid], h1 = hist[2 * tid + 1];
  u32 c0 = h0 >> 24, c1 = h1 >> 24;
  u32 excl = blockscan256_excl(c0 + c1, wsum);
  float d0 = rsqrtf(1.0f + (float)(h0 & 0xFFFFFFu) * (1.0f / 262144.0f));
  float d1 = rsqrtf(1.0f + (float)(h1 & 0xFFFFFFu) * (1.0f / 262144.0f));
  cur[2 * tid] = excl;
  cur[2 * tid + 1] = excl + c0;
  disl[2 * tid] = d0;
  disl[2 * tid + 1] = d1;
  int n0 = b * BNODES + 2 * tid;
  if (n0 < N) {
    dis[n0] = d0;
    info[n0] = make_int4((int)(s0 + excl), (int)c0, __float_as_int(d0), 0);
  }
  if (n0 + 1 < N) {
    dis[n0 + 1] = d1;
    info[n0 + 1] = make_int4((int)(s0 + excl + c0), (int)c1, __float_as_int(d1), 0);
  }
  __syncthreads();
  // pass 2: node-sort the bucket slice (L2-hot re-read), csr = {src, raw w}
  for (u32 p = s0 + tid; p < s1; p += 256) {
    uint2 ed = bucketed[p];
    u32 local = ed.x >> SRCBITS;
    u32 pos = atomicAdd(&cur[local], 1u);
    csr[s0 + pos] = make_int2((int)(ed.x & SRCMASK), (int)ed.y);
  }
  // pass 3: scale own H rows (H' = dis * H), coalesced uint2 rw
  uint2* Hv = (uint2*)H;
  for (int i = tid; i < BNODES * 16; i += 256) {
    int row = i >> 4;
    int node = b * BNODES + row;
    if (node >= N) break;                  // row monotone per thread
    float dv = disl[row];
    size_t idx = (size_t)node * 16 + (i & 15);
    uint2 v = Hv[idx];
    u32 lo = (u32)f2bf(bf_lo(v.x) * dv) | ((u32)f2bf(bf_hi(v.x) * dv) << 16);
    u32 hi = (u32)f2bf(bf_lo(v.y) * dv) | ((u32)f2bf(bf_hi(v.y) * dv) << 16);
    Hv[idx] = make_uint2(lo, hi);
  }
}

// ---- GEMM (layer 2): fp32 in, bf16 out, dis-scaled epilogue (H2' = dis*(Y@W2^T)) ----
__global__ void k_gemm(const float* __restrict__ X, const float* __restrict__ W,
                       const float* __restrict__ dis, u16* __restrict__ H, int N) {
  __shared__ float Wt[64][65];
  int tid = threadIdx.x;
  #pragma unroll
  for (int i = tid; i < 4096; i += 256) Wt[i & 63][i >> 6] = W[i];
  __syncthreads();
  int lane = tid & 63, wv = tid >> 6;
  int row0 = blockIdx.x * 16 + wv * 4;
  if (row0 >= N) return;
  if (row0 + 3 < N) {
    const float4* x0 = (const float4*)(X + (size_t)row0 * 64);
    float a0 = 0.f, a1 = 0.f, a2 = 0.f, a3 = 0.f;
    #pragma unroll
    for (int k4 = 0; k4 < 16; ++k4) {
      float4 xa = x0[k4];
      float4 xb = x0[16 + k4];
      float4 xc = x0[32 + k4];
      float4 xd = x0[48 + k4];
      int k = k4 << 2;
      float w0 = Wt[k][lane], w1 = Wt[k + 1][lane], w2 = Wt[k + 2][lane], w3 = Wt[k + 3][lane];
      a0 = fmaf(xa.x, w0, fmaf(xa.y, w1, fmaf(xa.z, w2, fmaf(xa.w, w3, a0))));
      a1 = fmaf(xb.x, w0, fmaf(xb.y, w1, fmaf(xb.z, w2, fmaf(xb.w, w3, a1))));
      a2 = fmaf(xc.x, w0, fmaf(xc.y, w1, fmaf(xc.z, w2, fmaf(xc.w, w3, a2))));
      a3 = fmaf(xd.x, w0, fmaf(xd.y, w1, fmaf(xd.z, w2, fmaf(xd.w, w3, a3))));
    }
    float dv0 = dis[row0], dv1 = dis[row0 + 1], dv2 = dis[row0 + 2], dv3 = dis[row0 + 3];
    H[(size_t)row0 * 64 + lane]       = f2bf(a0 * dv0);
    H[(size_t)(row0 + 1) * 64 + lane] = f2bf(a1 * dv1);
    H[(size_t)(row0 + 2) * 64 + lane] = f2bf(a2 * dv2);
    H[(size_t)(row0 + 3) * 64 + lane] = f2bf(a3 * dv3);
  } else {
    const float* x0 = X + (size_t)row0 * 64;
    for (int r = 0; r < 4 && row0 + r < N; ++r) {
      float a = 0.f;
      for (int k = 0; k < 64; ++k) a = fmaf(x0[r * 64 + k], Wt[k][lane], a);
      H[(size_t)(row0 + r) * 64 + lane] = f2bf(a * dis[row0 + r]);
    }
  }
}

// ---- aggregation: wave/node; 4 edge-groups x 16 lanes; unroll-4 clamped rounds.
// Rows pre-scaled (H' = dis*H); csr coef = RAW w; epilogue: dis_d*(acc+H'[d])+b.
template <int RELU>
__global__ __launch_bounds__(256, 6) void k_aggregate(
    const u16* __restrict__ H, const int4* __restrict__ info,
    const int2* __restrict__ csr, const float* __restrict__ bias,
    float* __restrict__ Y, int N) {
  int node = blockIdx.x * 4 + (threadIdx.x >> 6);
  if (node >= N) return;
  int lane = threadIdx.x & 63;
  int eg = lane >> 4;
  int fid = (lane & 15) << 2;
  int4 nfo = info[node];
  int s0 = nfo.x, n = nfo.y;
  float d = __int_as_float(nfo.z);
  uint2 hs = *(const uint2*)(H + (size_t)node * 64 + fid);   // pre-scaled self row
  float4 b4 = *(const float4*)(bias + fid);
  float4 acc = make_float4(0.f, 0.f, 0.f, 0.f);
  int nm1 = n - 1;
  for (int base = 0; base < n; base += 16) {
    int p0 = base + eg;
    int q0 = min(p0, nm1), q1 = min(p0 + 4, nm1);
    int q2 = min(p0 + 8, nm1), q3 = min(p0 + 12, nm1);
    int2 c0 = csr[s0 + q0];                                  // 4 csr loads in flight
    int2 c1 = csr[s0 + q1];
    int2 c2 = csr[s0 + q2];
    int2 c3 = csr[s0 + q3];
    uint2 h0 = *(const uint2*)(H + (size_t)c0.x * 64 + fid); // 4 gathers in flight
    uint2 h1 = *(const uint2*)(H + (size_t)c1.x * 64 + fid);
    uint2 h2 = *(const uint2*)(H + (size_t)c2.x * 64 + fid);
    uint2 h3 = *(const uint2*)(H + (size_t)c3.x * 64 + fid);
    float f0 = (p0      < n) ? __int_as_float(c0.y) : 0.f;   // OOB -> coef 0
    float f1 = (p0 + 4  < n) ? __int_as_float(c1.y) : 0.f;
    float f2 = (p0 + 8  < n) ? __int_as_float(c2.y) : 0.f;
    float f3 = (p0 + 12 < n) ? __int_as_float(c3.y) : 0.f;
    acc.x = fmaf(bf_lo(h0.x), f0, acc.x); acc.y = fmaf(bf_hi(h0.x), f0, acc.y);
    acc.z = fmaf(bf_lo(h0.y), f0, acc.z); acc.w = fmaf(bf_hi(h0.y), f0, acc.w);
    acc.x = fmaf(bf_lo(h1.x), f1, acc.x); acc.y = fmaf(bf_hi(h1.x), f1, acc.y);
    acc.z = fmaf(bf_lo(h1.y), f1, acc.z); acc.w = fmaf(bf_hi(h1.y), f1, acc.w);
    acc.x = fmaf(bf_lo(h2.x), f2, acc.x); acc.y = fmaf(bf_hi(h2.x), f2, acc.y);
    acc.z = fmaf(bf_lo(h2.y), f2, acc.z); acc.w = fmaf(bf_hi(h2.y), f2, acc.w);
    acc.x = fmaf(bf_lo(h3.x), f3, acc.x); acc.y = fmaf(bf_hi(h3.x), f3, acc.y);
    acc.z = fmaf(bf_lo(h3.y), f3, acc.z); acc.w = fmaf(bf_hi(h3.y), f3, acc.w);
  }
  acc.x += __shfl_xor(acc.x, 16); acc.y += __shfl_xor(acc.y, 16);
  acc.z += __shfl_xor(acc.z, 16); acc.w += __shfl_xor(acc.w, 16);
  acc.x += __shfl_xor(acc.x, 32); acc.y += __shfl_xor(acc.y, 32);
  acc.z += __shfl_xor(acc.z, 32); acc.w += __shfl_xor(acc.w, 32);
  if (eg == 0) {
    acc.x = (acc.x + bf_lo(hs.x)) * d + b4.x;
    acc.y = (acc.y + bf_hi(hs.x)) * d + b4.y;
    acc.z = (acc.z + bf_lo(hs.y)) * d + b4.z;
    acc.w = (acc.w + bf_hi(hs.y)) * d + b4.w;
    if (RELU) {
      acc.x = fmaxf(acc.x, 0.f); acc.y = fmaxf(acc.y, 0.f);
      acc.z = fmaxf(acc.z, 0.f); acc.w = fmaxf(acc.w, 0.f);
    }
    *(float4*)(Y + (size_t)node * 64 + fid) = acc;
  }
}

extern "C" void kernel_launch(void* const* d_in, const int* in_sizes, int n_in,
                              void* d_out, int out_size, void* d_ws, size_t ws_size,
                              hipStream_t stream) {
  const float* x  = (const float*)d_in[0];
  const int*   ei = (const int*)d_in[1];
  const float* w  = (const float*)d_in[2];
  const float* W1 = (const float*)d_in[3];
  const float* b1 = (const float*)d_in[4];
  const float* W2 = (const float*)d_in[5];
  const float* b2 = (const float*)d_in[6];
  const int N = in_sizes[0] / 64;
  const int E = in_sizes[2];

  char* ws = (char*)d_ws;
  size_t off = 0;
  auto alloc = [&](size_t bytes) -> char* {
    char* p = ws + off;
    off = (off + bytes + 255) & ~(size_t)255;
    return p;
  };
  u32*   blockcnt     = (u32*)  alloc((size_t)NBKT * 256 * 4);
  u32*   bucket_total = (u32*)  alloc((size_t)NBKT * 4);
  u32*   bucket_start = (u32*)  alloc((size_t)(NBKT + 1) * 4);
  uint2* bucketed     = (uint2*)alloc((size_t)E * 8);
  int2*  csr          = (int2*) alloc((size_t)E * 8);
  float* dis          = (float*)alloc((size_t)N * 4);
  int4*  info         = (int4*) alloc((size_t)N * 16);
  u16*   h1           = (u16*)  alloc((size_t)N * 64 * 2);
  u16*   h2           = (u16*)  alloc((size_t)N * 64 * 2);
  float* ybuf         = (float*)d_out;             // layer-1 activations (fp32)

  const int chunk = ((E + 511) / 512) * 2;         // even; 256 blocks cover E
  const int nbG = (N + 15) / 16;
  const int nbB = (N + BNODES - 1) >> LSH;         // 196 buckets

  k_bin<<<256, 256, 0, stream>>>(ei, blockcnt, E, chunk);
  k_scan_rows<<<NBKT / 4, 256, 0, stream>>>(blockcnt, bucket_total);
  k_scan_buckets<<<1, 256, 0, stream>>>(bucket_total, bucket_start);
  k_scatter_gemm<<<256 + nbG, 256, 0, stream>>>(ei, w, blockcnt, bucket_start,
                                                bucketed, x, W1, h1, N, E, chunk);
  k_statsfill<<<nbB, 256, 0, stream>>>(bucketed, bucket_start, dis, info, csr, h1, N);

  k_aggregate<1><<<(N + 3) / 4, 256, 0, stream>>>(h1, info, csr, b1, ybuf, N);
  k_gemm<<<nbG, 256, 0, stream>>>(ybuf, W2, dis, h2, N);
  k_aggregate<0><<<(N + 3) / 4, 256, 0, stream>>>(h2, info, csr, b2, (float*)d_out, N);
}